// Round 1
// 156.333 us; speedup vs baseline: 1.1483x; 1.1483x over previous
//
#include <hip/hip_runtime.h>
#include <math.h>

#define NH 64
#define NW 64
#define NB 4
#define CHI 256
#define CHO 256
#define XT_B (66 * 66 * 256)   // per-batch xT elements (zero-padded 66x66, ch-inner)

typedef __attribute__((ext_vector_type(8))) short bf16x8;   // MFMA A/B frag (4 VGPR)
typedef __attribute__((ext_vector_type(4))) float f32x4;    // MFMA C/D frag

static __device__ __forceinline__ unsigned short f2bf(float f) {
    unsigned int u = __float_as_uint(f);
    u += 0x7fffu + ((u >> 16) & 1u);     // RNE
    return (unsigned short)(u >> 16);
}
static __device__ __forceinline__ float bflo(unsigned int p) { return __uint_as_float(p << 16); }
static __device__ __forceinline__ float bfhi(unsigned int p) { return __uint_as_float(p & 0xffff0000u); }
// HW packed f32->bf16 RNE convert (no builtin on gfx950; 1 inst replaces ~9)
static __device__ __forceinline__ unsigned int pkbf(float a, float b) {
    unsigned int r;
    asm("v_cvt_pk_bf16_f32 %0, %1, %2" : "=v"(r) : "v"(a), "v"(b));
    return r;
}

// lgkm-only barrier: producer ds_writes / consumer ds_reads are drained, but
// in-flight global gathers (vmcnt) ride across the barrier into their own VGPRs.
// __syncthreads() would force vmcnt(0) and expose full gather latency per iter.
#define BAR_LGKM() asm volatile("s_waitcnt lgkmcnt(0)\n\ts_barrier" ::: "memory")

// ws layout:
//   wB   bf16 [72][256 o][32 kin]   ks = cc*9+kt, kin = channel within 32-chunk cc
//   wOB  bf16 [72][32 oc][32 kin]
//   xT   bf16 [B][66 yp][66 xp][256 c]  zero halo at yp/xp = 0,65 (halo blocks in prep)

// grid: [0,2304) wB pack | [2304,2592) wOB pack | [2592,3104) transpose | [3104,3624) halo zero
__global__ __launch_bounds__(256) void prep_all(const float* __restrict__ weight,
                                                const float* __restrict__ w_off,
                                                const float* __restrict__ x,
                                                unsigned short* __restrict__ wB,
                                                unsigned short* __restrict__ wOB,
                                                unsigned short* __restrict__ xT) {
    __shared__ unsigned short sT[64 * 134];
    int bid = blockIdx.x, tid = threadIdx.x;
    if (bid < 2304) {
        int idx = bid * 256 + tid;             // < 589824
        int kin = idx & 31, o = (idx >> 5) & 255, ks = idx >> 13;
        int cc = ks / 9, kt = ks - cc * 9;
        int c = cc * 32 + kin;
        wB[idx] = f2bf(weight[((size_t)o * CHI + c) * 9 + kt]);
    } else if (bid < 2592) {
        int idx = (bid - 2304) * 256 + tid;    // < 73728
        int kin = idx & 31, oc = (idx >> 5) & 31, ks = idx >> 10;
        int cc = ks / 9, kt = ks - cc * 9;
        int c = cc * 32 + kin;
        wOB[idx] = (oc < 27) ? f2bf(w_off[((size_t)oc * CHI + c) * 9 + kt])
                             : (unsigned short)0;
    } else if (bid < 3104) {
        // transpose half a (b,y) row-plane: x[b][c0..c0+128][y][*] f32 -> xT[b][y+1][*+1][c] bf16
        int bid2 = bid - 2592;                 // 0..511  (2 blocks/CU)
        int b = bid2 >> 7, rem = bid2 & 127;
        int y = rem >> 1, chalf = rem & 1;
        int c0 = chalf * 128;
        for (int rep = 0; rep < 8; ++rep) {
            int idx = rep * 256 + tid;         // 0..2047
            int c = idx >> 4, p4 = (idx & 15) * 4;
            const float* src = x + (((size_t)b * CHI + c0 + c) * 64 + y) * 64 + p4;
            float4 v = *(const float4*)src;
            sT[(p4 + 0) * 134 + c] = f2bf(v.x);
            sT[(p4 + 1) * 134 + c] = f2bf(v.y);
            sT[(p4 + 2) * 134 + c] = f2bf(v.z);
            sT[(p4 + 3) * 134 + c] = f2bf(v.w);
        }
        __syncthreads();
        unsigned int* dst = (unsigned int*)(xT + ((size_t)(b * 66 + y + 1) * 66 + 1) * 256)
                          + chalf * 64;
        for (int rep = 0; rep < 16; ++rep) {
            int idx = rep * 256 + tid;         // 0..4095
            int px = idx >> 6, cu = idx & 63;
            unsigned int lo = sT[px * 134 + cu * 2];
            unsigned int hi = sT[px * 134 + cu * 2 + 1];
            dst[(size_t)px * 128 + cu] = lo | (hi << 16);
        }
    } else {
        // zero the xT halo (rows y=0,65; cols x=0,65) -- ws is poisoned before each call
        int flat = (bid - 3104) * 256 + tid;   // 0..133119 uints
        int b = flat / 33280, r = flat - b * 33280;
        unsigned int* xtu = (unsigned int*)xT;
        size_t base = (size_t)b * 66 * 66 * 128;
        size_t idx;
        if (r < 8448) {
            idx = base + r;                                        // row y=0
        } else if (r < 16896) {
            idx = base + (size_t)65 * 66 * 128 + (r - 8448);       // row y=65
        } else {
            int rc = r - 16896;                                    // cols, rows 1..64
            int side = rc >> 13;
            int row = 1 + ((rc & 8191) >> 7);
            int cu = rc & 127;
            idx = base + ((size_t)row * 66 + (side ? 65 : 0)) * 128 + cu;
        }
        xtu[idx] = 0;
    }
}

// ---- fused: offset GEMM prologue + deformable sampling + MFMA GEMM + BN + ReLU ----
__global__ __launch_bounds__(512) void dcn_fused(
        const unsigned short* __restrict__ xT,
        const unsigned short* __restrict__ wOB,
        const unsigned short* __restrict__ wB,
        const float* __restrict__ b_off,
        const float* __restrict__ bias, const float* __restrict__ gamma,
        const float* __restrict__ beta, const float* __restrict__ rmean,
        const float* __restrict__ rvar, float* __restrict__ out) {
    // union'd LDS: {s_po, s_cw} fixed; sA region aliases sOff (prologue) and sOut (epilogue)
    __shared__ __align__(16) unsigned char smem[33280];
    int4*   s_po = (int4*)smem;                                 // [288] corner offsets
    float4* s_cw = (float4*)(smem + 4608);                      // [288] bilinear weights
    unsigned short* sA = (unsigned short*)(smem + 9216);        // [8][32*40] slice bufs
    float* sOff = (float*)(smem + 9216);                        // [2][32][33] offset partials
    float (*sOut)[260] = (float(*)[260])smem;                   // epilogue kh-combine

    int id = blockIdx.x;                        // 512 blocks
    int xcd = id & 7, sl = id >> 3;
    int b = xcd >> 1;
    int h = (xcd & 1) * 32 + (sl & 31);
    int pxbase = (sl >> 5) * 32;

    int tid = threadIdx.x;
    int lane = tid & 63, q = tid >> 6;
    int ln = lane & 15, lk = lane >> 4;
    int nb = q & 3, kh = q >> 2;                // main-loop consumer role

    const unsigned short* xTfull = xT + (size_t)b * XT_B;
    const bf16x8* wOBv = (const bf16x8*)wOB;
    const bf16x8* wBv  = (const bf16x8*)wB;

    // ---- offset-conv prologue: om = xT . wOB  (M=32 px, N=32 oc, K=2304) ----
    {
        int omt = q & 1, ont = (q >> 1) & 1, okq = q >> 2;   // wave -> (m-tile, n-tile, K-half)
        int opx = pxbase + omt * 16 + ln;
        int oposbase = (h + 1) * 66 + opx + 1;
        f32x4 oacc = {0.f, 0.f, 0.f, 0.f};
        for (int s = okq * 36; s < okq * 36 + 36; ++s) {
            int cc = s / 9, kt = s - cc * 9;
            int pos = oposbase + (kt / 3 - 1) * 66 + (kt % 3 - 1);
            bf16x8 af  = *(const bf16x8*)&xTfull[(size_t)pos * 256 + cc * 32 + lk * 8];
            bf16x8 bfo = wOBv[((size_t)s * 32 + ont * 16 + ln) * 4 + lk];
            oacc = __builtin_amdgcn_mfma_f32_16x16x32_bf16(af, bfo, oacc, 0, 0, 0);
        }
#pragma unroll
        for (int r = 0; r < 4; ++r)
            sOff[(okq * 32 + omt * 16 + lk * 4 + r) * 33 + ont * 16 + ln] = oacc[r];
    }
    BAR_LGKM();

    // ---- bilinear metadata from in-LDS offsets; sigmoid here ----
    for (int p = tid; p < 288; p += 512) {
        int k = p >> 5, pwl = p & 31, pw = pxbase + pwl;
        float dy = sOff[pwl * 33 + k]        + sOff[(32 + pwl) * 33 + k]        + b_off[k];
        float dx = sOff[pwl * 33 + k + 9]    + sOff[(32 + pwl) * 33 + k + 9]    + b_off[k + 9];
        float mp = sOff[pwl * 33 + k + 18]   + sOff[(32 + pwl) * 33 + k + 18]   + b_off[k + 18];
        float mv = 1.f / (1.f + __expf(-mp));
        float py  = (float)h  + (float)(k / 3 - 1) + dy;
        float pxf = (float)pw + (float)(k % 3 - 1) + dx;
        float y0f = floorf(py), x0f = floorf(pxf);
        int y0 = (int)y0f, x0 = (int)x0f;
        float ly = py - y0f, lx = pxf - x0f;
        int y0c = min(max(y0, -1), 64), y1c = min(max(y0 + 1, -1), 64);
        int x0c = min(max(x0, -1), 64), x1c = min(max(x0 + 1, -1), 64);
        int ry0 = (y0c + 1) * 66, ry1 = (y1c + 1) * 66;
        s_po[p] = make_int4(ry0 + x0c + 1, ry0 + x1c + 1, ry1 + x0c + 1, ry1 + x1c + 1);
        s_cw[p] = make_float4((1.f - ly) * (1.f - lx) * mv, (1.f - ly) * lx * mv,
                              ly * (1.f - lx) * mv,         ly * lx * mv);
    }

    // producer role: cg8 in the LOW lane bits so the 4 x 16B chunks of one 64B
    // corner record are fetched by 4 consecutive lanes of ONE instruction
    // (full-line TA coalescing; was split 2x32B across two waves).
    int cg8 = tid & 3, pxl = (tid >> 2) & 31, sl4 = tid >> 7;
    int khp = sl4 >> 1, ip = sl4 & 1;           // producer slice = khp*36 + 2*phase + ip
    const unsigned short* xTb = xTfull + cg8 * 8;

    f32x4 zf = {0.f, 0.f, 0.f, 0.f};
    f32x4 acc[2][4] = {{zf, zf, zf, zf}, {zf, zf, zf, zf}};

    uint4 C00, C01, C10, C11;

#define LOADS(s) do { int s_ = (s); int cc_ = s_ / 9; int kt_ = s_ - cc_ * 9;  \
        int4 o4_ = s_po[kt_ * 32 + pxl];                                       \
        const unsigned short* cb_ = xTb + cc_ * 32;                            \
        C00 = *(const uint4*)(cb_ + (size_t)o4_.x * 256);                      \
        C01 = *(const uint4*)(cb_ + (size_t)o4_.y * 256);                      \
        C10 = *(const uint4*)(cb_ + (size_t)o4_.z * 256);                      \
        C11 = *(const uint4*)(cb_ + (size_t)o4_.w * 256);                      \
    } while (0)

#define WRITEA(s, buf) do { int s_ = (s); int kt_ = s_ - (s_ / 9) * 9;         \
        float4 w_ = s_cw[kt_ * 32 + pxl];                                      \
        uint4 pk_;                                                             \
        pk_.x = pkbf(w_.x*bflo(C00.x)+w_.y*bflo(C01.x)+w_.z*bflo(C10.x)+w_.w*bflo(C11.x), \
                     w_.x*bfhi(C00.x)+w_.y*bfhi(C01.x)+w_.z*bfhi(C10.x)+w_.w*bfhi(C11.x)); \
        pk_.y = pkbf(w_.x*bflo(C00.y)+w_.y*bflo(C01.y)+w_.z*bflo(C10.y)+w_.w*bflo(C11.y), \
                     w_.x*bfhi(C00.y)+w_.y*bfhi(C01.y)+w_.z*bfhi(C10.y)+w_.w*bfhi(C11.y)); \
        pk_.z = pkbf(w_.x*bflo(C00.z)+w_.y*bflo(C01.z)+w_.z*bflo(C10.z)+w_.w*bflo(C11.z), \
                     w_.x*bfhi(C00.z)+w_.y*bfhi(C01.z)+w_.z*bfhi(C10.z)+w_.w*bfhi(C11.z)); \
        pk_.w = pkbf(w_.x*bflo(C00.w)+w_.y*bflo(C01.w)+w_.z*bflo(C10.w)+w_.w*bflo(C11.w), \
                     w_.x*bfhi(C00.w)+w_.y*bfhi(C01.w)+w_.z*bfhi(C10.w)+w_.w*bfhi(C11.w)); \
        *(uint4*)&sA[(buf) * 1280 + pxl * 40 + cg8 * 8] = pk_;                 \
    } while (0)

    BAR_LGKM();   // metadata ready; sOff no longer needed (sA may overwrite)

    // software pipeline prologue
    LOADS(khp * 36 + ip);
    WRITEA(khp * 36 + ip, sl4);
    LOADS(khp * 36 + 2 + ip);
    bf16x8 bf[4], nbf[4];
#pragma unroll
    for (int j = 0; j < 4; ++j)
        bf[j] = wBv[((size_t)(kh * 36) * 256 + nb * 64 + j * 16 + ln) * 4 + lk];
    BAR_LGKM();

    for (int g = 0; g < 18; ++g) {
        if (g + 1 < 18) WRITEA(khp * 36 + 2 * (g + 1) + ip, ((g + 1) & 1) * 4 + sl4);
        if (g + 2 < 18) LOADS(khp * 36 + 2 * (g + 2) + ip);
#pragma unroll
        for (int i = 0; i < 2; ++i) {           // consume this wave's 2 slices
            int off = 2 * g + i;                // 0..35 within K-half
            int buf = (g & 1) * 4 + kh * 2 + i;
            bf16x8 af0 = *(const bf16x8*)&sA[buf * 1280 + ln * 40 + lk * 8];
            bf16x8 af1 = *(const bf16x8*)&sA[buf * 1280 + (16 + ln) * 40 + lk * 8];
            bool more = (off + 1 < 36);
            if (more) {
                int sn = kh * 36 + off + 1;
#pragma unroll
                for (int j = 0; j < 4; ++j)
                    nbf[j] = wBv[((size_t)sn * 256 + nb * 64 + j * 16 + ln) * 4 + lk];
            }
#pragma unroll
            for (int j = 0; j < 4; ++j) {
                acc[0][j] = __builtin_amdgcn_mfma_f32_16x16x32_bf16(af0, bf[j], acc[0][j], 0, 0, 0);
                acc[1][j] = __builtin_amdgcn_mfma_f32_16x16x32_bf16(af1, bf[j], acc[1][j], 0, 0, 0);
            }
            if (more) {
#pragma unroll
                for (int j = 0; j < 4; ++j) bf[j] = nbf[j];
            }
        }
        // lgkm-only: the 4 gathers for g+2 (and next-slice weight frags) stay
        // in flight across the barrier instead of being drained by vmcnt(0).
        BAR_LGKM();
    }
#undef LOADS
#undef WRITEA

    // kh-combine + BN + ReLU epilogue (sOut aliases the K-phase LDS)
    if (kh == 1) {
#pragma unroll
        for (int m = 0; m < 2; ++m)
#pragma unroll
            for (int j = 0; j < 4; ++j) {
                int oc = nb * 64 + j * 16 + ln;
#pragma unroll
                for (int r = 0; r < 4; ++r)
                    sOut[m * 16 + lk * 4 + r][oc] = acc[m][j][r];
            }
    }
    __syncthreads();
    if (kh == 0) {
#pragma unroll
        for (int m = 0; m < 2; ++m)
#pragma unroll
            for (int j = 0; j < 4; ++j) {
                int oc = nb * 64 + j * 16 + ln;
                float inv = gamma[oc] * rsqrtf(rvar[oc] + 1e-5f);
                float sh  = beta[oc] - rmean[oc] * inv + bias[oc] * inv;
                int row = m * 16 + lk * 4;
                float4 rr;
                rr.x = fmaxf((acc[m][j][0] + sOut[row + 0][oc]) * inv + sh, 0.f);
                rr.y = fmaxf((acc[m][j][1] + sOut[row + 1][oc]) * inv + sh, 0.f);
                rr.z = fmaxf((acc[m][j][2] + sOut[row + 2][oc]) * inv + sh, 0.f);
                rr.w = fmaxf((acc[m][j][3] + sOut[row + 3][oc]) * inv + sh, 0.f);
                size_t oi = (((size_t)b * 256 + oc) * 64 + h) * 64 + pxbase + row;
                *(float4*)(out + oi) = rr;
            }
    }
}

extern "C" void kernel_launch(void* const* d_in, const int* in_sizes, int n_in,
                              void* d_out, int out_size, void* d_ws, size_t ws_size,
                              hipStream_t stream) {
    const float* x      = (const float*)d_in[0];
    const float* w_off  = (const float*)d_in[1];
    const float* b_off  = (const float*)d_in[2];
    const float* weight = (const float*)d_in[3];
    const float* bias   = (const float*)d_in[4];
    const float* gamma  = (const float*)d_in[5];
    const float* beta   = (const float*)d_in[6];
    const float* rmean  = (const float*)d_in[7];
    const float* rvar   = (const float*)d_in[8];
    float* out = (float*)d_out;

    unsigned short* wB  = (unsigned short*)d_ws;             // 589824 bf16
    unsigned short* wOB = wB + 589824;                       // 73728 bf16
    unsigned short* xT  = wOB + 73728;                       // 4 * 66*66*256 bf16

    hipLaunchKernelGGL(prep_all, dim3(3624), dim3(256), 0, stream,
                       weight, w_off, x, wB, wOB, xT);
    hipLaunchKernelGGL(dcn_fused, dim3(512), dim3(512), 0, stream,
                       xT, wOB, wB, b_off, bias, gamma, beta, rmean, rvar, out);
}

// Round 2
// 155.881 us; speedup vs baseline: 1.1516x; 1.0029x over previous
//
#include <hip/hip_runtime.h>
#include <math.h>

#define NH 64
#define NW 64
#define NB 4
#define CHI 256
#define CHO 256
#define XT_B (66 * 66 * 256)   // per-batch xT elements (zero-padded 66x66, ch-inner)

typedef __attribute__((ext_vector_type(8))) short bf16x8;   // MFMA A/B frag (4 VGPR)
typedef __attribute__((ext_vector_type(4))) float f32x4;    // MFMA C/D frag

static __device__ __forceinline__ unsigned short f2bf(float f) {
    unsigned int u = __float_as_uint(f);
    u += 0x7fffu + ((u >> 16) & 1u);     // RNE
    return (unsigned short)(u >> 16);
}
static __device__ __forceinline__ float bflo(unsigned int p) { return __uint_as_float(p << 16); }
static __device__ __forceinline__ float bfhi(unsigned int p) { return __uint_as_float(p & 0xffff0000u); }
// HW packed f32->bf16 RNE convert (no builtin on gfx950; 1 inst replaces ~9)
static __device__ __forceinline__ unsigned int pkbf(float a, float b) {
    unsigned int r;
    asm("v_cvt_pk_bf16_f32 %0, %1, %2" : "=v"(r) : "v"(a), "v"(b));
    return r;
}

// lgkm-only barrier: producer ds_writes / consumer ds_reads are drained, but
// in-flight global gathers (vmcnt) ride across the barrier into their own VGPRs.
// __syncthreads() would force vmcnt(0) and expose full gather latency per iter.
#define BAR_LGKM() asm volatile("s_waitcnt lgkmcnt(0)\n\ts_barrier" ::: "memory")

// ws layout:
//   wB   bf16 [72][256 o][32 kin]   ks = cc*9+kt, kin = channel within 32-chunk cc
//   wOB  bf16 [72][32 oc][32 kin]
//   xT   bf16 [B][66 yp][66 xp][256 c]  zero halo at yp/xp = 0,65 (halo blocks in prep)

// grid: [0,2304) wB pack | [2304,2592) wOB pack | [2592,3104) transpose | [3104,3624) halo zero
__global__ __launch_bounds__(256) void prep_all(const float* __restrict__ weight,
                                                const float* __restrict__ w_off,
                                                const float* __restrict__ x,
                                                unsigned short* __restrict__ wB,
                                                unsigned short* __restrict__ wOB,
                                                unsigned short* __restrict__ xT) {
    __shared__ unsigned short sT[64 * 134];
    int bid = blockIdx.x, tid = threadIdx.x;
    if (bid < 2304) {
        int idx = bid * 256 + tid;             // < 589824
        int kin = idx & 31, o = (idx >> 5) & 255, ks = idx >> 13;
        int cc = ks / 9, kt = ks - cc * 9;
        int c = cc * 32 + kin;
        wB[idx] = f2bf(weight[((size_t)o * CHI + c) * 9 + kt]);
    } else if (bid < 2592) {
        int idx = (bid - 2304) * 256 + tid;    // < 73728
        int kin = idx & 31, oc = (idx >> 5) & 31, ks = idx >> 10;
        int cc = ks / 9, kt = ks - cc * 9;
        int c = cc * 32 + kin;
        wOB[idx] = (oc < 27) ? f2bf(w_off[((size_t)oc * CHI + c) * 9 + kt])
                             : (unsigned short)0;
    } else if (bid < 3104) {
        // transpose half a (b,y) row-plane: x[b][c0..c0+128][y][*] f32 -> xT[b][y+1][*+1][c] bf16
        int bid2 = bid - 2592;                 // 0..511  (2 blocks/CU)
        int b = bid2 >> 7, rem = bid2 & 127;
        int y = rem >> 1, chalf = rem & 1;
        int c0 = chalf * 128;
        for (int rep = 0; rep < 8; ++rep) {
            int idx = rep * 256 + tid;         // 0..2047
            int c = idx >> 4, p4 = (idx & 15) * 4;
            const float* src = x + (((size_t)b * CHI + c0 + c) * 64 + y) * 64 + p4;
            float4 v = *(const float4*)src;
            sT[(p4 + 0) * 134 + c] = f2bf(v.x);
            sT[(p4 + 1) * 134 + c] = f2bf(v.y);
            sT[(p4 + 2) * 134 + c] = f2bf(v.z);
            sT[(p4 + 3) * 134 + c] = f2bf(v.w);
        }
        __syncthreads();
        unsigned int* dst = (unsigned int*)(xT + ((size_t)(b * 66 + y + 1) * 66 + 1) * 256)
                          + chalf * 64;
        for (int rep = 0; rep < 16; ++rep) {
            int idx = rep * 256 + tid;         // 0..4095
            int px = idx >> 6, cu = idx & 63;
            unsigned int lo = sT[px * 134 + cu * 2];
            unsigned int hi = sT[px * 134 + cu * 2 + 1];
            dst[(size_t)px * 128 + cu] = lo | (hi << 16);
        }
    } else {
        // zero the xT halo (rows y=0,65; cols x=0,65) -- ws is poisoned before each call
        int flat = (bid - 3104) * 256 + tid;   // 0..133119 uints
        int b = flat / 33280, r = flat - b * 33280;
        unsigned int* xtu = (unsigned int*)xT;
        size_t base = (size_t)b * 66 * 66 * 128;
        size_t idx;
        if (r < 8448) {
            idx = base + r;                                        // row y=0
        } else if (r < 16896) {
            idx = base + (size_t)65 * 66 * 128 + (r - 8448);       // row y=65
        } else {
            int rc = r - 16896;                                    // cols, rows 1..64
            int side = rc >> 13;
            int row = 1 + ((rc & 8191) >> 7);
            int cu = rc & 127;
            idx = base + ((size_t)row * 66 + (side ? 65 : 0)) * 128 + cu;
        }
        xtu[idx] = 0;
    }
}

// ---- fused: offset GEMM prologue + deformable sampling + MFMA GEMM + BN + ReLU ----
// __launch_bounds__(512, 4): grid is 512 blocks = 2 blocks/CU = 16 waves/CU = 4 waves/EU.
// Without the hint the compiler targets the LDS-derived 8 waves/EU and caps VGPRs at ~56,
// which collapses the software pipeline (loads sunk to just-before-use). 4 waves/EU
// gives a 128-VGPR budget -- enough for acc(32) + C(16) + 2x weight sets(32) + af(16).
__global__ __launch_bounds__(512, 4) void dcn_fused(
        const unsigned short* __restrict__ xT,
        const unsigned short* __restrict__ wOB,
        const unsigned short* __restrict__ wB,
        const float* __restrict__ b_off,
        const float* __restrict__ bias, const float* __restrict__ gamma,
        const float* __restrict__ beta, const float* __restrict__ rmean,
        const float* __restrict__ rvar, float* __restrict__ out) {
    // union'd LDS: {s_po, s_cw} fixed; sA region aliases sOff (prologue) and sOut (epilogue)
    __shared__ __align__(16) unsigned char smem[33280];
    int4*   s_po = (int4*)smem;                                 // [288] corner offsets
    float4* s_cw = (float4*)(smem + 4608);                      // [288] bilinear weights
    unsigned short* sA = (unsigned short*)(smem + 9216);        // [8][32*40] slice bufs
    float* sOff = (float*)(smem + 9216);                        // [2][32][33] offset partials
    float (*sOut)[260] = (float(*)[260])smem;                   // epilogue kh-combine

    int id = blockIdx.x;                        // 512 blocks
    int xcd = id & 7, sl = id >> 3;
    int b = xcd >> 1;
    int h = (xcd & 1) * 32 + (sl & 31);
    int pxbase = (sl >> 5) * 32;

    int tid = threadIdx.x;
    int lane = tid & 63, q = tid >> 6;
    int ln = lane & 15, lk = lane >> 4;
    int nb = q & 3, kh = q >> 2;                // main-loop consumer role

    const unsigned short* xTfull = xT + (size_t)b * XT_B;
    const bf16x8* wOBv = (const bf16x8*)wOB;
    const bf16x8* wBv  = (const bf16x8*)wB;

    // ---- offset-conv prologue: om = xT . wOB  (M=32 px, N=32 oc, K=2304) ----
    // nested cc/kt with unrolled kt: no runtime /9, /3, %3; 9 independent loads per
    // cc-block for the scheduler to pipeline; dual accumulators break the serial chain.
    {
        int omt = q & 1, ont = (q >> 1) & 1, okq = q >> 2;   // wave -> (m-tile, n-tile, K-half)
        int opx = pxbase + omt * 16 + ln;
        int oposbase = (h + 1) * 66 + opx + 1;
        f32x4 oa0 = {0.f, 0.f, 0.f, 0.f}, oa1 = {0.f, 0.f, 0.f, 0.f};
        for (int cc = okq * 4; cc < okq * 4 + 4; ++cc) {
#pragma unroll
            for (int kt = 0; kt < 9; ++kt) {
                int pos = oposbase + (kt / 3 - 1) * 66 + (kt % 3 - 1);
                bf16x8 af = *(const bf16x8*)&xTfull[(size_t)pos * 256 + cc * 32 + lk * 8];
                bf16x8 bo = wOBv[((size_t)(cc * 9 + kt) * 32 + ont * 16 + ln) * 4 + lk];
                if (kt & 1) oa1 = __builtin_amdgcn_mfma_f32_16x16x32_bf16(af, bo, oa1, 0, 0, 0);
                else        oa0 = __builtin_amdgcn_mfma_f32_16x16x32_bf16(af, bo, oa0, 0, 0, 0);
            }
        }
#pragma unroll
        for (int r = 0; r < 4; ++r)
            sOff[(okq * 32 + omt * 16 + lk * 4 + r) * 33 + ont * 16 + ln] = oa0[r] + oa1[r];
    }
    BAR_LGKM();

    // ---- bilinear metadata from in-LDS offsets; sigmoid here ----
    for (int p = tid; p < 288; p += 512) {
        int k = p >> 5, pwl = p & 31, pw = pxbase + pwl;
        float dy = sOff[pwl * 33 + k]        + sOff[(32 + pwl) * 33 + k]        + b_off[k];
        float dx = sOff[pwl * 33 + k + 9]    + sOff[(32 + pwl) * 33 + k + 9]    + b_off[k + 9];
        float mp = sOff[pwl * 33 + k + 18]   + sOff[(32 + pwl) * 33 + k + 18]   + b_off[k + 18];
        float mv = 1.f / (1.f + __expf(-mp));
        float py  = (float)h  + (float)(k / 3 - 1) + dy;
        float pxf = (float)pw + (float)(k % 3 - 1) + dx;
        float y0f = floorf(py), x0f = floorf(pxf);
        int y0 = (int)y0f, x0 = (int)x0f;
        float ly = py - y0f, lx = pxf - x0f;
        int y0c = min(max(y0, -1), 64), y1c = min(max(y0 + 1, -1), 64);
        int x0c = min(max(x0, -1), 64), x1c = min(max(x0 + 1, -1), 64);
        int ry0 = (y0c + 1) * 66, ry1 = (y1c + 1) * 66;
        s_po[p] = make_int4(ry0 + x0c + 1, ry0 + x1c + 1, ry1 + x0c + 1, ry1 + x1c + 1);
        s_cw[p] = make_float4((1.f - ly) * (1.f - lx) * mv, (1.f - ly) * lx * mv,
                              ly * (1.f - lx) * mv,         ly * lx * mv);
    }

    // producer role: cg8 in the LOW lane bits so the 4 x 16B chunks of one 64B
    // corner record are fetched by 4 consecutive lanes of ONE instruction.
    int cg8 = tid & 3, pxl = (tid >> 2) & 31, sl4 = tid >> 7;
    int khp = sl4 >> 1, ip = sl4 & 1;           // producer slice = khp*36 + 2*phase + ip
    const unsigned short* xTb = xTfull + cg8 * 8;

    f32x4 zf = {0.f, 0.f, 0.f, 0.f};
    f32x4 acc[2][4] = {{zf, zf, zf, zf}, {zf, zf, zf, zf}};

    uint4 C00, C01, C10, C11;

#define LOADS(s) do { int s_ = (s); int cc_ = s_ / 9; int kt_ = s_ - cc_ * 9;  \
        int4 o4_ = s_po[kt_ * 32 + pxl];                                       \
        const unsigned short* cb_ = xTb + cc_ * 32;                            \
        C00 = *(const uint4*)(cb_ + (size_t)o4_.x * 256);                      \
        C01 = *(const uint4*)(cb_ + (size_t)o4_.y * 256);                      \
        C10 = *(const uint4*)(cb_ + (size_t)o4_.z * 256);                      \
        C11 = *(const uint4*)(cb_ + (size_t)o4_.w * 256);                      \
    } while (0)

#define WRITEA(s, buf) do { int s_ = (s); int kt_ = s_ - (s_ / 9) * 9;         \
        float4 w_ = s_cw[kt_ * 32 + pxl];                                      \
        uint4 pk_;                                                             \
        pk_.x = pkbf(w_.x*bflo(C00.x)+w_.y*bflo(C01.x)+w_.z*bflo(C10.x)+w_.w*bflo(C11.x), \
                     w_.x*bfhi(C00.x)+w_.y*bfhi(C01.x)+w_.z*bfhi(C10.x)+w_.w*bfhi(C11.x)); \
        pk_.y = pkbf(w_.x*bflo(C00.y)+w_.y*bflo(C01.y)+w_.z*bflo(C10.y)+w_.w*bflo(C11.y), \
                     w_.x*bfhi(C00.y)+w_.y*bfhi(C01.y)+w_.z*bfhi(C10.y)+w_.w*bfhi(C11.y)); \
        pk_.z = pkbf(w_.x*bflo(C00.z)+w_.y*bflo(C01.z)+w_.z*bflo(C10.z)+w_.w*bflo(C11.z), \
                     w_.x*bfhi(C00.z)+w_.y*bfhi(C01.z)+w_.z*bfhi(C10.z)+w_.w*bfhi(C11.z)); \
        pk_.w = pkbf(w_.x*bflo(C00.w)+w_.y*bflo(C01.w)+w_.z*bflo(C10.w)+w_.w*bflo(C11.w), \
                     w_.x*bfhi(C00.w)+w_.y*bfhi(C01.w)+w_.z*bfhi(C10.w)+w_.w*bfhi(C11.w)); \
        *(uint4*)&sA[(buf) * 1280 + pxl * 40 + cg8 * 8] = pk_;                 \
    } while (0)

    BAR_LGKM();   // metadata ready; sOff no longer needed (sA may overwrite)

    // software pipeline prologue
    LOADS(khp * 36 + ip);
    WRITEA(khp * 36 + ip, sl4);
    LOADS(khp * 36 + 2 + ip);
    // weight register double-buffer: even/odd slice sets, refilled 2 slices ahead
    bf16x8 bfE[4], bfO[4];
#pragma unroll
    for (int j = 0; j < 4; ++j) {
        bfE[j] = wBv[((size_t)(kh * 36 + 0) * 256 + nb * 64 + j * 16 + ln) * 4 + lk];
        bfO[j] = wBv[((size_t)(kh * 36 + 1) * 256 + nb * 64 + j * 16 + ln) * 4 + lk];
    }
    BAR_LGKM();

    for (int g = 0; g < 18; ++g) {
        if (g + 1 < 18) WRITEA(khp * 36 + 2 * (g + 1) + ip, ((g + 1) & 1) * 4 + sl4);
        if (g + 2 < 18) LOADS(khp * 36 + 2 * (g + 2) + ip);

        // both A-fragment pairs for this g are complete behind the barrier --
        // issue all 4 ds_reads up front so i=1 never waits mid-iteration.
        int bufb = (g & 1) * 4 + kh * 2;
        const unsigned short* pA0 = &sA[bufb * 1280];
        const unsigned short* pA1 = &sA[bufb * 1280 + 1280];
        bf16x8 a00 = *(const bf16x8*)&pA0[ln * 40 + lk * 8];
        bf16x8 a01 = *(const bf16x8*)&pA0[(16 + ln) * 40 + lk * 8];
        bf16x8 a10 = *(const bf16x8*)&pA1[ln * 40 + lk * 8];
        bf16x8 a11 = *(const bf16x8*)&pA1[(16 + ln) * 40 + lk * 8];

#pragma unroll
        for (int j = 0; j < 4; ++j) {
            acc[0][j] = __builtin_amdgcn_mfma_f32_16x16x32_bf16(a00, bfE[j], acc[0][j], 0, 0, 0);
            acc[1][j] = __builtin_amdgcn_mfma_f32_16x16x32_bf16(a01, bfE[j], acc[1][j], 0, 0, 0);
        }
        if (2 * g + 2 < 36) {       // refill even set, consumed 2 slices (~1 g) later
#pragma unroll
            for (int j = 0; j < 4; ++j)
                bfE[j] = wBv[((size_t)(kh * 36 + 2 * g + 2) * 256 + nb * 64 + j * 16 + ln) * 4 + lk];
        }
#pragma unroll
        for (int j = 0; j < 4; ++j) {
            acc[0][j] = __builtin_amdgcn_mfma_f32_16x16x32_bf16(a10, bfO[j], acc[0][j], 0, 0, 0);
            acc[1][j] = __builtin_amdgcn_mfma_f32_16x16x32_bf16(a11, bfO[j], acc[1][j], 0, 0, 0);
        }
        if (2 * g + 3 < 36) {       // refill odd set
#pragma unroll
            for (int j = 0; j < 4; ++j)
                bfO[j] = wBv[((size_t)(kh * 36 + 2 * g + 3) * 256 + nb * 64 + j * 16 + ln) * 4 + lk];
        }
        // lgkm-only: in-flight gathers/weight loads ride across the barrier.
        BAR_LGKM();
    }
#undef LOADS
#undef WRITEA

    // kh-combine + BN + ReLU epilogue (sOut aliases the K-phase LDS)
    if (kh == 1) {
#pragma unroll
        for (int m = 0; m < 2; ++m)
#pragma unroll
            for (int j = 0; j < 4; ++j) {
                int oc = nb * 64 + j * 16 + ln;
#pragma unroll
                for (int r = 0; r < 4; ++r)
                    sOut[m * 16 + lk * 4 + r][oc] = acc[m][j][r];
            }
    }
    __syncthreads();
    if (kh == 0) {
#pragma unroll
        for (int j = 0; j < 4; ++j) {
            int oc = nb * 64 + j * 16 + ln;
            float inv = gamma[oc] * rsqrtf(rvar[oc] + 1e-5f);
            float sh  = beta[oc] - rmean[oc] * inv + bias[oc] * inv;
#pragma unroll
            for (int m = 0; m < 2; ++m) {
                int row = m * 16 + lk * 4;
                float4 rr;
                rr.x = fmaxf((acc[m][j][0] + sOut[row + 0][oc]) * inv + sh, 0.f);
                rr.y = fmaxf((acc[m][j][1] + sOut[row + 1][oc]) * inv + sh, 0.f);
                rr.z = fmaxf((acc[m][j][2] + sOut[row + 2][oc]) * inv + sh, 0.f);
                rr.w = fmaxf((acc[m][j][3] + sOut[row + 3][oc]) * inv + sh, 0.f);
                size_t oi = (((size_t)b * 256 + oc) * 64 + h) * 64 + pxbase + row;
                *(float4*)(out + oi) = rr;
            }
        }
    }
}

extern "C" void kernel_launch(void* const* d_in, const int* in_sizes, int n_in,
                              void* d_out, int out_size, void* d_ws, size_t ws_size,
                              hipStream_t stream) {
    const float* x      = (const float*)d_in[0];
    const float* w_off  = (const float*)d_in[1];
    const float* b_off  = (const float*)d_in[2];
    const float* weight = (const float*)d_in[3];
    const float* bias   = (const float*)d_in[4];
    const float* gamma  = (const float*)d_in[5];
    const float* beta   = (const float*)d_in[6];
    const float* rmean  = (const float*)d_in[7];
    const float* rvar   = (const float*)d_in[8];
    float* out = (float*)d_out;

    unsigned short* wB  = (unsigned short*)d_ws;             // 589824 bf16
    unsigned short* wOB = wB + 589824;                       // 73728 bf16
    unsigned short* xT  = wOB + 73728;                       // 4 * 66*66*256 bf16

    hipLaunchKernelGGL(prep_all, dim3(3624), dim3(256), 0, stream,
                       weight, w_off, x, wB, wOB, xT);
    hipLaunchKernelGGL(dcn_fused, dim3(512), dim3(512), 0, stream,
                       xT, wOB, wB, b_off, bias, gamma, beta, rmean, rvar, out);
}

// Round 3
// 138.675 us; speedup vs baseline: 1.2945x; 1.1241x over previous
//
#include <hip/hip_runtime.h>
#include <math.h>

#define NH 64
#define NW 64
#define NB 4
#define CHI 256
#define CHO 256
#define XT_B (66 * 66 * 256)   // per-batch xT elements (zero-padded 66x66, ch-inner)

typedef __attribute__((ext_vector_type(8))) short bf16x8;   // MFMA A/B frag (4 VGPR)
typedef __attribute__((ext_vector_type(4))) float f32x4;    // MFMA C/D frag

static __device__ __forceinline__ unsigned short f2bf(float f) {
    unsigned int u = __float_as_uint(f);
    u += 0x7fffu + ((u >> 16) & 1u);     // RNE
    return (unsigned short)(u >> 16);
}
static __device__ __forceinline__ float bflo(unsigned int p) { return __uint_as_float(p << 16); }
static __device__ __forceinline__ float bfhi(unsigned int p) { return __uint_as_float(p & 0xffff0000u); }
// HW packed f32->bf16 RNE convert
static __device__ __forceinline__ unsigned int pkbf(float a, float b) {
    unsigned int r;
    asm("v_cvt_pk_bf16_f32 %0, %1, %2" : "=v"(r) : "v"(a), "v"(b));
    return r;
}

// lgkm-only barrier: ds ops drained, in-flight global gathers ride across.
#define BAR_LGKM() asm volatile("s_waitcnt lgkmcnt(0)\n\ts_barrier" ::: "memory")

// ws layout:
//   wB   bf16 [72][256 o][32 kin]   ks = cc*9+kt, kin = channel within 32-chunk cc
//   wOB  bf16 [72][32 oc][32 kin]
//   xT   bf16 [B][66 yp][66 xp][256 c]  zero halo at yp/xp = 0,65

// grid: [0,2304) wB pack | [2304,2592) wOB pack | [2592,3104) transpose | [3104,3624) halo zero
__global__ __launch_bounds__(256) void prep_all(const float* __restrict__ weight,
                                                const float* __restrict__ w_off,
                                                const float* __restrict__ x,
                                                unsigned short* __restrict__ wB,
                                                unsigned short* __restrict__ wOB,
                                                unsigned short* __restrict__ xT) {
    __shared__ unsigned short sT[64 * 134];
    int bid = blockIdx.x, tid = threadIdx.x;
    if (bid < 2304) {
        int idx = bid * 256 + tid;             // < 589824
        int kin = idx & 31, o = (idx >> 5) & 255, ks = idx >> 13;
        int cc = ks / 9, kt = ks - cc * 9;
        int c = cc * 32 + kin;
        wB[idx] = f2bf(weight[((size_t)o * CHI + c) * 9 + kt]);
    } else if (bid < 2592) {
        int idx = (bid - 2304) * 256 + tid;    // < 73728
        int kin = idx & 31, oc = (idx >> 5) & 31, ks = idx >> 10;
        int cc = ks / 9, kt = ks - cc * 9;
        int c = cc * 32 + kin;
        wOB[idx] = (oc < 27) ? f2bf(w_off[((size_t)oc * CHI + c) * 9 + kt])
                             : (unsigned short)0;
    } else if (bid < 3104) {
        int bid2 = bid - 2592;                 // 0..511
        int b = bid2 >> 7, rem = bid2 & 127;
        int y = rem >> 1, chalf = rem & 1;
        int c0 = chalf * 128;
        for (int rep = 0; rep < 8; ++rep) {
            int idx = rep * 256 + tid;         // 0..2047
            int c = idx >> 4, p4 = (idx & 15) * 4;
            const float* src = x + (((size_t)b * CHI + c0 + c) * 64 + y) * 64 + p4;
            float4 v = *(const float4*)src;
            sT[(p4 + 0) * 134 + c] = f2bf(v.x);
            sT[(p4 + 1) * 134 + c] = f2bf(v.y);
            sT[(p4 + 2) * 134 + c] = f2bf(v.z);
            sT[(p4 + 3) * 134 + c] = f2bf(v.w);
        }
        __syncthreads();
        unsigned int* dst = (unsigned int*)(xT + ((size_t)(b * 66 + y + 1) * 66 + 1) * 256)
                          + chalf * 64;
        for (int rep = 0; rep < 16; ++rep) {
            int idx = rep * 256 + tid;         // 0..4095
            int px = idx >> 6, cu = idx & 63;
            unsigned int lo = sT[px * 134 + cu * 2];
            unsigned int hi = sT[px * 134 + cu * 2 + 1];
            dst[(size_t)px * 128 + cu] = lo | (hi << 16);
        }
    } else {
        int flat = (bid - 3104) * 256 + tid;   // 0..133119 uints
        int b = flat / 33280, r = flat - b * 33280;
        unsigned int* xtu = (unsigned int*)xT;
        size_t base = (size_t)b * 66 * 66 * 128;
        size_t idx;
        if (r < 8448) {
            idx = base + r;
        } else if (r < 16896) {
            idx = base + (size_t)65 * 66 * 128 + (r - 8448);
        } else {
            int rc = r - 16896;
            int side = rc >> 13;
            int row = 1 + ((rc & 8191) >> 7);
            int cu = rc & 127;
            idx = base + ((size_t)row * 66 + (side ? 65 : 0)) * 128 + cu;
        }
        xtu[idx] = 0;
    }
}

// ---- fused: offset GEMM prologue + deformable sampling + MFMA GEMM + BN + ReLU ----
// 256 blocks (1/CU), 512 threads. Block = one (b,h) output row: M=64 px, N=256 oc.
// Doubling M per block halves the per-call wB re-read traffic (590->295 MB of L2),
// which was ~half the TA segment floor. 8 waves: nb(4) x kh(2); each wave carries
// 4 A-frags (acc[4][4] = 64 regs) -> needs the 256-reg budget of 2 waves/SIMD.
__global__ __launch_bounds__(512, 2) void dcn_fused(
        const unsigned short* __restrict__ xT,
        const unsigned short* __restrict__ wOB,
        const unsigned short* __restrict__ wB,
        const float* __restrict__ b_off,
        const float* __restrict__ bias, const float* __restrict__ gamma,
        const float* __restrict__ beta, const float* __restrict__ rmean,
        const float* __restrict__ rvar, float* __restrict__ out) {
    // LDS: s_po/s_cw fixed @[0,18432); sA slice bufs @[18432,59392) aliased by
    // sOff (prologue partials, 33792B); sOut (epilogue, 66560B) aliases everything.
    __shared__ __align__(16) unsigned char smem[66560];
    int4*   s_po = (int4*)smem;                                 // [576] corner offsets
    float4* s_cw = (float4*)(smem + 9216);                      // [576] bilinear weights
    unsigned short* sA = (unsigned short*)(smem + 18432);       // [8][64*40] slice bufs
    float* sOff = (float*)(smem + 18432);                       // [4][64][33] offset partials
    float (*sOut)[260] = (float(*)[260])smem;                   // [64][260] epilogue

    int id = blockIdx.x;                        // 256 blocks
    int xcd = id & 7, sl = id >> 3;             // 32 blocks per XCD
    int b = xcd >> 1;                           // batch pinned to an XCD pair (xT L2 reuse)
    int h = (xcd & 1) * 32 + sl;                // output row

    int tid = threadIdx.x;
    int lane = tid & 63, q = tid >> 6;
    int ln = lane & 15, lk = lane >> 4;
    int nb = q & 3, kh = q >> 2;                // consumer role: 64-oc group, K-half

    const unsigned short* xTfull = xT + (size_t)b * XT_B;
    const bf16x8* wOBv = (const bf16x8*)wOB;
    const bf16x8* wBv  = (const bf16x8*)wB;

    // ---- offset-conv prologue: om = xT . wOB  (M=64 px, N=32 oc, K=2304) ----
    // roles: omt = px 32-half, okq = K-quarter (2 cc each); full 32 oc per wave.
    {
        int omt = q & 1, okq = q >> 1;
        int px0 = omt * 32 + ln;
        int posb = (h + 1) * 66 + 1 + px0;
        f32x4 oa00 = {0.f,0.f,0.f,0.f}, oa01 = {0.f,0.f,0.f,0.f};
        f32x4 oa10 = {0.f,0.f,0.f,0.f}, oa11 = {0.f,0.f,0.f,0.f};
        for (int cc = okq * 2; cc < okq * 2 + 2; ++cc) {
#pragma unroll
            for (int kt = 0; kt < 9; ++kt) {
                int pos = posb + (kt / 3 - 1) * 66 + (kt % 3 - 1);
                bf16x8 A0 = *(const bf16x8*)&xTfull[(size_t)pos * 256 + cc * 32 + lk * 8];
                bf16x8 A1 = *(const bf16x8*)&xTfull[(size_t)(pos + 16) * 256 + cc * 32 + lk * 8];
                bf16x8 B0 = wOBv[((size_t)(cc * 9 + kt) * 32 + ln) * 4 + lk];
                bf16x8 B1 = wOBv[((size_t)(cc * 9 + kt) * 32 + 16 + ln) * 4 + lk];
                oa00 = __builtin_amdgcn_mfma_f32_16x16x32_bf16(A0, B0, oa00, 0, 0, 0);
                oa01 = __builtin_amdgcn_mfma_f32_16x16x32_bf16(A0, B1, oa01, 0, 0, 0);
                oa10 = __builtin_amdgcn_mfma_f32_16x16x32_bf16(A1, B0, oa10, 0, 0, 0);
                oa11 = __builtin_amdgcn_mfma_f32_16x16x32_bf16(A1, B1, oa11, 0, 0, 0);
            }
        }
#pragma unroll
        for (int r = 0; r < 4; ++r) {
            int row0 = okq * 64 + omt * 32 + lk * 4 + r;
            sOff[row0 * 33 + ln]            = oa00[r];
            sOff[row0 * 33 + 16 + ln]       = oa01[r];
            sOff[(row0 + 16) * 33 + ln]     = oa10[r];
            sOff[(row0 + 16) * 33 + 16 + ln]= oa11[r];
        }
    }
    BAR_LGKM();

    // ---- bilinear metadata from in-LDS offsets (4 K-quarter partials) ----
    for (int p = tid; p < 576; p += 512) {
        int k = p >> 6, pwl = p & 63;
        float dy = b_off[k], dx = b_off[k + 9], mp = b_off[k + 18];
#pragma unroll
        for (int jq = 0; jq < 4; ++jq) {
            dy += sOff[(jq * 64 + pwl) * 33 + k];
            dx += sOff[(jq * 64 + pwl) * 33 + k + 9];
            mp += sOff[(jq * 64 + pwl) * 33 + k + 18];
        }
        float mv = 1.f / (1.f + __expf(-mp));
        float py  = (float)h   + (float)(k / 3 - 1) + dy;
        float pxf = (float)pwl + (float)(k % 3 - 1) + dx;
        float y0f = floorf(py), x0f = floorf(pxf);
        int y0 = (int)y0f, x0 = (int)x0f;
        float ly = py - y0f, lx = pxf - x0f;
        int y0c = min(max(y0, -1), 64), y1c = min(max(y0 + 1, -1), 64);
        int x0c = min(max(x0, -1), 64), x1c = min(max(x0 + 1, -1), 64);
        int ry0 = (y0c + 1) * 66, ry1 = (y1c + 1) * 66;
        s_po[p] = make_int4(ry0 + x0c + 1, ry0 + x1c + 1, ry1 + x0c + 1, ry1 + x1c + 1);
        s_cw[p] = make_float4((1.f - ly) * (1.f - lx) * mv, (1.f - ly) * lx * mv,
                              ly * (1.f - lx) * mv,         ly * lx * mv);
    }

    // producer role: thread = (cg8 0..3 low bits for 64B coalescing, pxl 0..63, khp half)
    int cg8 = tid & 3, pxl = (tid >> 2) & 63, khp = tid >> 8;
    const unsigned short* xTb = xTfull + cg8 * 8;

    f32x4 zf = {0.f, 0.f, 0.f, 0.f};
    f32x4 acc[4][4] = {{zf,zf,zf,zf},{zf,zf,zf,zf},{zf,zf,zf,zf},{zf,zf,zf,zf}};

    uint4 P0, P1, P2, P3;   // gather set for slice ip=0
    uint4 Q0, Q1, Q2, Q3;   // gather set for slice ip=1

#define LOADSET(s, A0_, A1_, A2_, A3_) do { int s_ = (s);                      \
        int cc_ = s_ / 9; int kt_ = s_ - cc_ * 9;                              \
        int4 o4_ = s_po[kt_ * 64 + pxl];                                       \
        const unsigned short* cb_ = xTb + cc_ * 32;                            \
        A0_ = *(const uint4*)(cb_ + (size_t)o4_.x * 256);                      \
        A1_ = *(const uint4*)(cb_ + (size_t)o4_.y * 256);                      \
        A2_ = *(const uint4*)(cb_ + (size_t)o4_.z * 256);                      \
        A3_ = *(const uint4*)(cb_ + (size_t)o4_.w * 256);                      \
    } while (0)

#define WRITESET(s, buf, A0_, A1_, A2_, A3_) do { int s_ = (s);                \
        int kt_ = s_ - (s_ / 9) * 9;                                           \
        float4 w_ = s_cw[kt_ * 64 + pxl];                                      \
        uint4 pk_;                                                             \
        pk_.x = pkbf(w_.x*bflo(A0_.x)+w_.y*bflo(A1_.x)+w_.z*bflo(A2_.x)+w_.w*bflo(A3_.x), \
                     w_.x*bfhi(A0_.x)+w_.y*bfhi(A1_.x)+w_.z*bfhi(A2_.x)+w_.w*bfhi(A3_.x)); \
        pk_.y = pkbf(w_.x*bflo(A0_.y)+w_.y*bflo(A1_.y)+w_.z*bflo(A2_.y)+w_.w*bflo(A3_.y), \
                     w_.x*bfhi(A0_.y)+w_.y*bfhi(A1_.y)+w_.z*bfhi(A2_.y)+w_.w*bfhi(A3_.y)); \
        pk_.z = pkbf(w_.x*bflo(A0_.z)+w_.y*bflo(A1_.z)+w_.z*bflo(A2_.z)+w_.w*bflo(A3_.z), \
                     w_.x*bfhi(A0_.z)+w_.y*bfhi(A1_.z)+w_.z*bfhi(A2_.z)+w_.w*bfhi(A3_.z)); \
        pk_.w = pkbf(w_.x*bflo(A0_.w)+w_.y*bflo(A1_.w)+w_.z*bflo(A2_.w)+w_.w*bflo(A3_.w), \
                     w_.x*bfhi(A0_.w)+w_.y*bfhi(A1_.w)+w_.z*bfhi(A2_.w)+w_.w*bfhi(A3_.w)); \
        *(uint4*)&sA[(buf) * 2560 + pxl * 40 + cg8 * 8] = pk_;                 \
    } while (0)

    BAR_LGKM();   // metadata ready; sOff region may now be overwritten by sA

    // software pipeline prologue: fill slots for g=0, issue gathers for g=1
    LOADSET(khp * 36 + 0, P0, P1, P2, P3);
    LOADSET(khp * 36 + 1, Q0, Q1, Q2, Q3);
    WRITESET(khp * 36 + 0, khp * 2 + 0, P0, P1, P2, P3);
    WRITESET(khp * 36 + 1, khp * 2 + 1, Q0, Q1, Q2, Q3);
    LOADSET(khp * 36 + 2, P0, P1, P2, P3);
    LOADSET(khp * 36 + 3, Q0, Q1, Q2, Q3);

    // weight register double-buffer: even/odd slice sets, refilled 2 slices ahead
    bf16x8 bfE[4], bfO[4];
#pragma unroll
    for (int j = 0; j < 4; ++j) {
        bfE[j] = wBv[((size_t)(kh * 36 + 0) * 256 + nb * 64 + j * 16 + ln) * 4 + lk];
        bfO[j] = wBv[((size_t)(kh * 36 + 1) * 256 + nb * 64 + j * 16 + ln) * 4 + lk];
    }
    BAR_LGKM();

    for (int g = 0; g < 18; ++g) {
        if (g + 1 < 18) {
            int base = ((g + 1) & 1) * 4 + khp * 2;
            WRITESET(khp * 36 + 2 * (g + 1),     base,     P0, P1, P2, P3);
            WRITESET(khp * 36 + 2 * (g + 1) + 1, base + 1, Q0, Q1, Q2, Q3);
        }
        if (g + 2 < 18) {
            LOADSET(khp * 36 + 2 * (g + 2),     P0, P1, P2, P3);
            LOADSET(khp * 36 + 2 * (g + 2) + 1, Q0, Q1, Q2, Q3);
        }

        // consume this wave's 2 slices (4 m-frags each), written last iteration
        int slotb = (g & 1) * 4 + kh * 2;
        const unsigned short* pA0 = &sA[slotb * 2560];
        const unsigned short* pA1 = &sA[(slotb + 1) * 2560];
        bf16x8 a0[4], a1[4];
#pragma unroll
        for (int m = 0; m < 4; ++m) a0[m] = *(const bf16x8*)&pA0[(m * 16 + ln) * 40 + lk * 8];
#pragma unroll
        for (int m = 0; m < 4; ++m) a1[m] = *(const bf16x8*)&pA1[(m * 16 + ln) * 40 + lk * 8];

#pragma unroll
        for (int m = 0; m < 4; ++m)
#pragma unroll
            for (int j = 0; j < 4; ++j)
                acc[m][j] = __builtin_amdgcn_mfma_f32_16x16x32_bf16(a0[m], bfE[j], acc[m][j], 0, 0, 0);
        if (2 * g + 2 < 36) {
#pragma unroll
            for (int j = 0; j < 4; ++j)
                bfE[j] = wBv[((size_t)(kh * 36 + 2 * g + 2) * 256 + nb * 64 + j * 16 + ln) * 4 + lk];
        }
#pragma unroll
        for (int m = 0; m < 4; ++m)
#pragma unroll
            for (int j = 0; j < 4; ++j)
                acc[m][j] = __builtin_amdgcn_mfma_f32_16x16x32_bf16(a1[m], bfO[j], acc[m][j], 0, 0, 0);
        if (2 * g + 3 < 36) {
#pragma unroll
            for (int j = 0; j < 4; ++j)
                bfO[j] = wBv[((size_t)(kh * 36 + 2 * g + 3) * 256 + nb * 64 + j * 16 + ln) * 4 + lk];
        }
        BAR_LGKM();
    }
#undef LOADSET
#undef WRITESET

    // kh-combine + BN + ReLU epilogue (sOut aliases all working LDS)
    if (kh == 1) {
#pragma unroll
        for (int m = 0; m < 4; ++m)
#pragma unroll
            for (int j = 0; j < 4; ++j) {
                int oc = nb * 64 + j * 16 + ln;
#pragma unroll
                for (int r = 0; r < 4; ++r)
                    sOut[m * 16 + lk * 4 + r][oc] = acc[m][j][r];
            }
    }
    __syncthreads();
    if (kh == 0) {
#pragma unroll
        for (int j = 0; j < 4; ++j) {
            int oc = nb * 64 + j * 16 + ln;
            float inv = gamma[oc] * rsqrtf(rvar[oc] + 1e-5f);
            float sh  = beta[oc] - rmean[oc] * inv + bias[oc] * inv;
#pragma unroll
            for (int m = 0; m < 4; ++m) {
                int row = m * 16 + lk * 4;
                float4 rr;
                rr.x = fmaxf((acc[m][j][0] + sOut[row + 0][oc]) * inv + sh, 0.f);
                rr.y = fmaxf((acc[m][j][1] + sOut[row + 1][oc]) * inv + sh, 0.f);
                rr.z = fmaxf((acc[m][j][2] + sOut[row + 2][oc]) * inv + sh, 0.f);
                rr.w = fmaxf((acc[m][j][3] + sOut[row + 3][oc]) * inv + sh, 0.f);
                size_t oi = (((size_t)b * 256 + oc) * 64 + h) * 64 + row;
                *(float4*)(out + oi) = rr;
            }
        }
    }
}

extern "C" void kernel_launch(void* const* d_in, const int* in_sizes, int n_in,
                              void* d_out, int out_size, void* d_ws, size_t ws_size,
                              hipStream_t stream) {
    const float* x      = (const float*)d_in[0];
    const float* w_off  = (const float*)d_in[1];
    const float* b_off  = (const float*)d_in[2];
    const float* weight = (const float*)d_in[3];
    const float* bias   = (const float*)d_in[4];
    const float* gamma  = (const float*)d_in[5];
    const float* beta   = (const float*)d_in[6];
    const float* rmean  = (const float*)d_in[7];
    const float* rvar   = (const float*)d_in[8];
    float* out = (float*)d_out;

    unsigned short* wB  = (unsigned short*)d_ws;             // 589824 bf16
    unsigned short* wOB = wB + 589824;                       // 73728 bf16
    unsigned short* xT  = wOB + 73728;                       // 4 * 66*66*256 bf16

    hipLaunchKernelGGL(prep_all, dim3(3624), dim3(256), 0, stream,
                       weight, w_off, x, wB, wOB, xT);
    hipLaunchKernelGGL(dcn_fused, dim3(256), dim3(512), 0, stream,
                       xT, wOB, wB, b_off, bias, gamma, beta, rmean, rvar, out);
}